// Round 18
// baseline (114.502 us; speedup 1.0000x reference)
//
#include <hip/hip_runtime.h>

typedef __attribute__((ext_vector_type(4))) float  f32x4;
typedef __attribute__((ext_vector_type(8))) short  bf16x8;
typedef __attribute__((ext_vector_type(4))) int    i32x4;

#define NB 16      // batch
#define NN 2048    // nodes
#define FF 64      // features

// combined dequant scale: A scale 127, U fixed-point scale 2^11
#define INV_SCALE (1.0f / (127.0f * 2048.0f))

// round-to-nearest-even f32 -> bf16 bits
__device__ __forceinline__ unsigned short f2bf(float x) {
  union { float f; unsigned int u; } c; c.f = x;
  unsigned int u = c.u;
  return (unsigned short)((u + 0x7fffu + ((u >> 16) & 1u)) >> 16);
}
__device__ __forceinline__ float bf2f(unsigned short b) {
  union { unsigned int u; float f; } c; c.u = (unsigned int)b << 16;
  return c.f;
}
__device__ __forceinline__ unsigned int fbits(float x) {
  union { float f; unsigned int u; } c; c.f = x; return c.u;
}

__device__ __forceinline__ void gload16(const void* g, void* l) {
  __builtin_amdgcn_global_load_lds(
      (const __attribute__((address_space(1))) void*)g,
      (__attribute__((address_space(3))) void*)l, 16, 0, 0);
}

#define BAR() asm volatile("s_barrier" ::: "memory")

// Pass 1 [R18: transpose fused in]. One wave per row:
//   - full-row f32 sum (butterfly -> all lanes), d = 1/(eps+sqrt(s - A[i][i]))
//   - A row -> i8 (magic-number RNE, v_perm pack, contiguous 16B/lane)
//   - diag byte patched post-drain; dvec written
//   - X row quantized in-wave: Tb0[row][f]=bf16(X), Uq[b][f][row]=i8(2048*d*X)
// Blocks >= NB*NN/4 convert the weight: WT[c][k] = bf16(Kr[k][c]).
// [R9: A-side at HBM roofline; fused X-side adds ~3% traffic, kills a kernel]
__global__ __launch_bounds__(256) void rowsum_conv_kernel(
    const float* __restrict__ A, char* __restrict__ A8,
    float* __restrict__ dvec,
    const float* __restrict__ X, char* __restrict__ Uq,
    unsigned short* __restrict__ Tb,
    const float* __restrict__ Kr, unsigned short* __restrict__ WT) {
  if (blockIdx.x >= NB * NN / 4) {
    int idx = (blockIdx.x - NB * NN / 4) * 256 + threadIdx.x;  // < 32768
    int k = idx >> 7, c = idx & 127;
    WT[c * 256 + k] = f2bf(Kr[idx]);
    return;
  }
  int row = blockIdx.x * 4 + (threadIdx.x >> 6);
  int lane = threadIdx.x & 63;
  int i = row & (NN - 1);
  int b = row >> 11;                      // NN = 2048
  const float* arow = A + (size_t)row * NN;
  char* orow = A8 + (size_t)row * NN;
  float diagval = __builtin_nontemporal_load(arow + i);  // broadcast load
  float s = 0.f;
#pragma unroll
  for (int p = 0; p < 8; ++p) {
    int base = p * 256 + lane * 4;
    f32x4 v = __builtin_nontemporal_load((const f32x4*)(arow + base));
    s += v[0] + v[1] + v[2] + v[3];
    float y0 = fmaf(v[0], 127.f, 8388608.f);
    float y1 = fmaf(v[1], 127.f, 8388608.f);
    float y2 = fmaf(v[2], 127.f, 8388608.f);
    float y3 = fmaf(v[3], 127.f, 8388608.f);
    // perm sel: 0x0C = constant 0x00; take low byte of each rounded value
    unsigned p01 = __builtin_amdgcn_perm(fbits(y1), fbits(y0), 0x0C0C0400u);
    unsigned p23 = __builtin_amdgcn_perm(fbits(y3), fbits(y2), 0x0C0C0400u);
    *(unsigned int*)(orow + base) =
        __builtin_amdgcn_perm(p23, p01, 0x05040100u);
  }
#pragma unroll
  for (int off = 32; off > 0; off >>= 1) s += __shfl_xor(s, off, 64);
  float d = 1.0f / (1e-6f + sqrtf(s - diagval));
  asm volatile("s_waitcnt vmcnt(0)" ::: "memory");  // packed stores done
  if (lane == 0) {
    orow[i] = 0;                                    // zero the diag byte
    dvec[row] = d;
  }
  // fused X-side: this wave owns row -> T0 & U0 for its 64 features
  float x = X[(size_t)row * FF + lane];
  Tb[(size_t)row * FF + lane] = f2bf(x);
  int q = (int)rintf(x * d * 2048.f);
  q = q > 127 ? 127 : (q < -127 ? -127 : q);
  Uq[((size_t)b * FF + lane) * NN + i] = (char)q;
}

// C = A8[b] (64 x 2048) @ U (2048 x 64), single-plane i8:
//   v = cs * d[n] * C_int - prevb[n][f](bf16)   (cs includes 1/(127*2048))
//   Tbout = bf16(v); Uqout = clamp(rint(d*v*2048), +-127) transposed via LDS.
// [R16 config — best measured. Cheb is at its practical HBM roofline:
// per-step staging 32KB/CU at ~24B/cyc/CU dominates; A8 not L3-retained
// (per-replay rowsum flood evicts). R11/R13/R14/R17 falsified occupancy/
// LDS-bytes/depth/step-size as levers.] 8 waves, BK=128, 2-deep unified
// stage, steady vmcnt(2), 128B rows, slot^(row&7) swizzle, XCD-pinned b.
__global__ __launch_bounds__(512) void cheb_mm_kernel(
    const char* __restrict__ A8,
    const char* __restrict__ Uq,
    const float* __restrict__ dvec,
    const unsigned short* __restrict__ prevb,   // nullable
    unsigned short* __restrict__ Tbout,
    char* __restrict__ Uqout,                   // nullable
    float cs) {
  __shared__ char lds[32768];  // A: 2x8K @0; U: 2x8K @16384
  int bid = blockIdx.x;
  int slot = bid >> 3;
  int b = (bid & 7) * 2 + (slot >> 5);   // XCD-pinned: 2 batches per XCD
  int tm = slot & 31;
  int tid = threadIdx.x;
  int lane = tid & 63;
  int w = tid >> 6;                      // 0..7
  int wm = w >> 1, wn = w & 1;           // 4 row-groups x 2 col-groups
  int lr = lane >> 3;                    // row 0..7 within an 8-row chunk
  int gs = (lane & 7) ^ lr;              // inverse-swizzled source slot (16B)
  int r16 = lane & 15, kq = lane >> 4;
  const int NT = NN / 128;               // 16 super-steps

  const size_t abase = ((size_t)b * NN + (size_t)tm * 64) * NN;
  const size_t ubase = (size_t)b * FF * NN;

  i32x4 acc[2] = {};   // A @ U  (ni = 0,1)

  int r = w * 8 + lr;                    // this thread's staged row 0..63
  auto stage = [&](int s, int kt) {      // 2 gloads per wave (U, A)
    int k0 = kt * 128;
    gload16(Uq + ubase + (size_t)r * NN + k0 + gs * 16,
            &lds[16384 + s * 8192 + w * 1024]);
    gload16(A8 + abase + (size_t)r * NN + k0 + gs * 16,
            &lds[s * 8192 + w * 1024]);
  };

  // prologue: both buffers (prefetch distance 2)
  stage(0, 0); stage(1, 1);
  for (int t = 0; t < NT; ++t) {
    int s = t & 1;
    if (t < NT - 1) asm volatile("s_waitcnt vmcnt(2)" ::: "memory");
    else            asm volatile("s_waitcnt vmcnt(0)" ::: "memory");
    BAR();                                  // bufs ready for all waves
    int ar = wm * 16 + r16;
#pragma unroll
    for (int j = 0; j < 2; ++j) {           // 2 k-substeps of 64
      i32x4 af = *(const i32x4*)&lds[s * 8192 + ar * 128 +
                                     (((j * 4 + kq) ^ (ar & 7)) * 16)];
#pragma unroll
      for (int ni = 0; ni < 2; ++ni) {
        int fr = wn * 32 + ni * 16 + r16;
        int fo = fr * 128 + (((j * 4 + kq) ^ (fr & 7)) * 16);
        i32x4 uf = *(const i32x4*)&lds[16384 + s * 8192 + fo];
        acc[ni] = __builtin_amdgcn_mfma_i32_16x16x64_i8(af, uf, acc[ni], 0, 0, 0);
      }
    }
    BAR();                                  // all waves done reading buf s
    if (t + 2 < NT) stage(s, t + 2);
  }

  // epilogue: D mapping col=lane&15, row=(lane>>4)*4+reg (dtype-independent)
  char (*tq)[72] = (char(*)[72])lds;       // 64 cols x 64 rows @0
  int n0 = tm * 64;
#pragma unroll
  for (int rg = 0; rg < 4; ++rg) {
    int rl = wm * 16 + kq * 4 + rg;
    int row = n0 + rl;
    float dd = dvec[b * NN + row];
    float dcs = dd * cs;
#pragma unroll
    for (int ni = 0; ni < 2; ++ni) {
      int col = wn * 32 + ni * 16 + r16;
      size_t idx = ((size_t)b * NN + row) * FF + col;
      float v = dcs * (float)acc[ni][rg];
      if (prevb) v -= bf2f(prevb[idx]);
      Tbout[idx] = f2bf(v);
      if (Uqout) {
        int q = (int)rintf(dd * v * 2048.f);
        q = q > 127 ? 127 : (q < -127 ? -127 : q);
        tq[col][rl] = (char)q;
      }
    }
  }
  if (Uqout) {
    __syncthreads();
    int f = tid >> 3, nb = (tid & 7) * 8;     // 512 threads = 64 f x 8 chunks
    unsigned long long vq = *(const unsigned long long*)&tq[f][nb];
    *(unsigned long long*)&Uqout[((size_t)b * FF + f) * NN + n0 + nb] = vq;
  }
}

// out[m][c] = relu( sum_k Z[m][k]*W[k][c] + bias[c] ), Z = [Tb0|Tb1|Tb2|Tb3]
// BM=64, BN=128, BK=64; 4 waves (2x2), wave tile 32x64; 3-deep counted-vmcnt.
__global__ __launch_bounds__(256) void final_gemm_kernel(
    const unsigned short* __restrict__ Tb,   // [4][M][64] bf16
    const unsigned short* __restrict__ WT,   // [128][256] bf16
    const float* __restrict__ bias,
    float* __restrict__ out) {
  __shared__ unsigned short lds[36864];   // A: 3 x 4096 at 0; B: 3 x 8192 at 12288
  const int M = NB * NN;
  int m0 = blockIdx.x * 64;
  int tid = threadIdx.x;
  int lane = tid & 63, w = tid >> 6;
  int wm = w >> 1, wn = w & 1;
  int lr = lane >> 3, gs = (lane & 7) ^ lr;
  int r16 = lane & 15, kq = lane >> 4;

  f32x4 acc[2][4] = {};

  auto stage = [&](int s, int kt) {   // 6 gload16 per wave
    const unsigned short* asrc = Tb + (size_t)kt * M * FF;
#pragma unroll
    for (int i = 0; i < 2; ++i) {
      int chunk = w * 2 + i;                   // 8 chunks: 64 rows
      int r = chunk * 8 + lr;
      gload16(asrc + (size_t)(m0 + r) * FF + gs * 8,
              &lds[s * 4096 + chunk * 512]);
    }
#pragma unroll
    for (int i = 0; i < 4; ++i) {
      int chunk = w * 4 + i;                   // 16 chunks: 128 c-rows
      int c = chunk * 8 + lr;
      gload16(WT + c * 256 + kt * 64 + gs * 8,
              &lds[12288 + s * 8192 + chunk * 512]);
    }
  };

  stage(0, 0); stage(1, 1); stage(2, 2);
  int s = 0;
  for (int t = 0; t < 4; ++t) {
    if (t < 2)       asm volatile("s_waitcnt vmcnt(12)" ::: "memory");
    else if (t == 2) asm volatile("s_waitcnt vmcnt(6)" ::: "memory");
    else             asm volatile("s_waitcnt vmcnt(0)" ::: "memory");
    BAR();
    bf16x8 af[2][2], bfr[4][2];
#pragma unroll
    for (int ks = 0; ks < 2; ++ks) {
#pragma unroll
      for (int mi = 0; mi < 2; ++mi) {
        int row = wm * 32 + mi * 16 + r16;
        af[mi][ks] = *(const bf16x8*)&lds[s * 4096 + row * 64 +
                                          (((ks * 4 + kq) ^ (row & 7)) * 8)];
      }
#pragma unroll
      for (int ni = 0; ni < 4; ++ni) {
        int fr = wn * 64 + ni * 16 + r16;
        bfr[ni][ks] = *(const bf16x8*)&lds[12288 + s * 8192 + fr * 64 +
                                           (((ks * 4 + kq) ^ (fr & 7)) * 8)];
      }
    }
#pragma unroll
    for (int ks = 0; ks < 2; ++ks)
#pragma unroll
      for (int mi = 0; mi < 2; ++mi)
#pragma unroll
        for (int ni = 0; ni < 4; ++ni)
          acc[mi][ni] = __builtin_amdgcn_mfma_f32_16x16x32_bf16(
              af[mi][ks], bfr[ni][ks], acc[mi][ni], 0, 0, 0);
    BAR();
    if (t + 3 < 4) stage(s, t + 3);
    s = (s == 2) ? 0 : s + 1;
  }

#pragma unroll
  for (int mi = 0; mi < 2; ++mi) {
#pragma unroll
    for (int r = 0; r < 4; ++r) {
      int row = m0 + wm * 32 + mi * 16 + kq * 4 + r;
#pragma unroll
      for (int ni = 0; ni < 4; ++ni) {
        int col = wn * 64 + ni * 16 + r16;
        float v = acc[mi][ni][r] + bias[col];
        out[(size_t)row * 128 + col] = v > 0.f ? v : 0.f;
      }
    }
  }
}

extern "C" void kernel_launch(void* const* d_in, const int* in_sizes, int n_in,
                              void* d_out, int out_size, void* d_ws, size_t ws_size,
                              hipStream_t stream) {
  const float* X    = (const float*)d_in[0];   // [16,2048,64]
  const float* A    = (const float*)d_in[1];   // [16,2048,2048]
  const float* Kr   = (const float*)d_in[2];   // [256,128]
  const float* bias = (const float*)d_in[3];   // [128]
  float* out = (float*)d_out;
  char* ws = (char*)d_ws;

  const size_t SZ_A8 = (size_t)NB * NN * NN;       // 67 MB i8 A
  const size_t SZ_D  = (size_t)NB * NN * 4;
  const size_t SZ_U  = (size_t)NB * FF * NN;       // 2 MB i8 U plane
  const size_t SZ_TB = (size_t)NB * NN * FF * 2;   // 4 MB per bf16 slab
  const size_t TBE   = (size_t)NB * NN * FF;       // elements per Tb slab

  char*           A8  = ws;
  float*          dv  = (float*)(ws + SZ_A8);
  char*           Ua  = ws + SZ_A8 + SZ_D;
  char*           Ub  = Ua + SZ_U;
  unsigned short* Tb  = (unsigned short*)(Ub + SZ_U);
  unsigned short* WT  = (unsigned short*)(Ub + SZ_U + 4 * SZ_TB);

  // rowsum + fused T0/U0 quant + WT convert (extra 128 blocks)
  rowsum_conv_kernel<<<NB * NN / 4 + 128, 256, 0, stream>>>(
      A, A8, dv, X, Ua, Tb, Kr, WT);
  // T1 = d ⊙ (A @ U0);        Tb1, Ub
  cheb_mm_kernel<<<512, 512, 0, stream>>>(A8, Ua, dv, nullptr,
                                          Tb + TBE, Ub, 1.0f * INV_SCALE);
  // T2 = 2 d ⊙ (A @ U1) - T0; Tb2, Ua
  cheb_mm_kernel<<<512, 512, 0, stream>>>(A8, Ub, dv, Tb,
                                          Tb + 2 * TBE, Ua, 2.0f * INV_SCALE);
  // T3 = 2 d ⊙ (A @ U2) - T1; Tb3
  cheb_mm_kernel<<<512, 512, 0, stream>>>(A8, Ua, dv, Tb + TBE,
                                          Tb + 3 * TBE, nullptr, 2.0f * INV_SCALE);
  final_gemm_kernel<<<512, 256, 0, stream>>>(Tb, WT, bias, out);
}

// Round 19
// 113.470 us; speedup vs baseline: 1.0091x; 1.0091x over previous
//
#include <hip/hip_runtime.h>

typedef __attribute__((ext_vector_type(4))) float  f32x4;
typedef __attribute__((ext_vector_type(8))) short  bf16x8;
typedef __attribute__((ext_vector_type(4))) int    i32x4;
typedef __attribute__((ext_vector_type(4))) unsigned short u16x4;

#define NB 16      // batch
#define NN 2048    // nodes
#define FF 64      // features

// combined dequant scale: A scale 127, U fixed-point scale 2^11
#define INV_SCALE (1.0f / (127.0f * 2048.0f))

// round-to-nearest-even f32 -> bf16 bits
__device__ __forceinline__ unsigned short f2bf(float x) {
  union { float f; unsigned int u; } c; c.f = x;
  unsigned int u = c.u;
  return (unsigned short)((u + 0x7fffu + ((u >> 16) & 1u)) >> 16);
}
__device__ __forceinline__ float bf2f(unsigned short b) {
  union { unsigned int u; float f; } c; c.u = (unsigned int)b << 16;
  return c.f;
}
__device__ __forceinline__ unsigned int fbits(float x) {
  union { float f; unsigned int u; } c; c.f = x; return c.u;
}

__device__ __forceinline__ void gload16(const void* g, void* l) {
  __builtin_amdgcn_global_load_lds(
      (const __attribute__((address_space(1))) void*)g,
      (__attribute__((address_space(3))) void*)l, 16, 0, 0);
}

#define BAR() asm volatile("s_barrier" ::: "memory")

// Pass 1: one wave per row. Magic-number RNE quantization; contiguous lane
// indexing. Diag via full-sum minus A[i][i]; diag byte patched post-drain.
// [R9 measured: 54.8 us = HBM floor for 335 MB. At roofline.]
__global__ __launch_bounds__(256) void rowsum_conv_kernel(
    const float* __restrict__ A, char* __restrict__ A8,
    float* __restrict__ dvec) {
  int row = blockIdx.x * 4 + (threadIdx.x >> 6);
  int lane = threadIdx.x & 63;
  int i = row & (NN - 1);
  const float* arow = A + (size_t)row * NN;
  char* orow = A8 + (size_t)row * NN;
  float diagval = __builtin_nontemporal_load(arow + i);  // broadcast load
  float s = 0.f;
#pragma unroll
  for (int p = 0; p < 8; ++p) {
    int base = p * 256 + lane * 4;
    f32x4 v = __builtin_nontemporal_load((const f32x4*)(arow + base));
    s += v[0] + v[1] + v[2] + v[3];
    float y0 = fmaf(v[0], 127.f, 8388608.f);
    float y1 = fmaf(v[1], 127.f, 8388608.f);
    float y2 = fmaf(v[2], 127.f, 8388608.f);
    float y3 = fmaf(v[3], 127.f, 8388608.f);
    // perm sel: 0x0C = constant 0x00; take low byte of each rounded value
    unsigned p01 = __builtin_amdgcn_perm(fbits(y1), fbits(y0), 0x0C0C0400u);
    unsigned p23 = __builtin_amdgcn_perm(fbits(y3), fbits(y2), 0x0C0C0400u);
    *(unsigned int*)(orow + base) =
        __builtin_amdgcn_perm(p23, p01, 0x05040100u);
  }
#pragma unroll
  for (int off = 32; off > 0; off >>= 1) s += __shfl_down(s, off, 64);
  asm volatile("s_waitcnt vmcnt(0)" ::: "memory");  // packed stores done
  if (lane == 0) {
    orow[i] = 0;                                    // zero the diag byte
    dvec[row] = 1.0f / (1e-6f + sqrtf(s - diagval));
  }
}

// blocks 0..511: Uq[b][f][n] = clamp(rint(d*X*2048), +-127); Tb = bf16(X)
// blocks 512..639: WT[c][k] = bf16(Kr[k][c])
__global__ __launch_bounds__(256) void scale_transpose_kernel(
    const float* __restrict__ V, const float* __restrict__ dvec,
    char* __restrict__ Uq,
    unsigned short* __restrict__ Tb,
    const float* __restrict__ Kr, unsigned short* __restrict__ WT) {
  int bid = blockIdx.x;
  int tid = threadIdx.x;
  if (bid >= 512) {
    int idx = (bid - 512) * 256 + tid;     // < 32768
    int k = idx >> 7, c = idx & 127;
    WT[c * 256 + k] = f2bf(Kr[idx]);
    return;
  }
  int b = bid >> 5;
  int n0 = (bid & 31) * 64;
  __shared__ float t[64][65];
#pragma unroll
  for (int it = 0; it < 4; ++it) {
    int e = it * 256 + tid;                // 1024 groups of 4 elements
    int nl = e >> 4;
    int f0 = (e & 15) * 4;
    int n = n0 + nl;
    f32x4 v = *(const f32x4*)&V[((size_t)b * NN + n) * FF + f0];
    float dd = dvec[b * NN + n];
    u16x4 o;
#pragma unroll
    for (int j = 0; j < 4; ++j) { o[j] = f2bf(v[j]); t[f0 + j][nl] = v[j] * dd; }
    *(u16x4*)&Tb[((size_t)b * NN + n) * FF + f0] = o;
  }
  __syncthreads();
#pragma unroll
  for (int it = 0; it < 2; ++it) {
    int c = it * 256 + tid;                // 512 groups of 8
    int f = c >> 3, nl0 = (c & 7) * 8;
    unsigned long long pq = 0;
#pragma unroll
    for (int j = 0; j < 8; ++j) {
      int q = (int)rintf(t[f][nl0 + j] * 2048.f);
      q = q > 127 ? 127 : (q < -127 ? -127 : q);
      pq |= (unsigned long long)((unsigned int)q & 255u) << (8 * j);
    }
    *(unsigned long long*)&Uq[((size_t)b * FF + f) * NN + n0 + nl0] = pq;
  }
}

// C = A8[b] (64 x 2048) @ U (2048 x 64), single-plane i8:
//   v = cs * d[n] * C_int - prevb[n][f](bf16)   (cs includes 1/(127*2048))
//   Tbout = bf16(v); Uqout = clamp(rint(d*v*2048), +-127) transposed via LDS.
// [R16 config — empirical best. Cheb ~82% of its per-pass HBM floor; six
// structural levers (R11/R13/R14/R17 occupancy, LDS-bytes, depth, step-size)
// all falsified for the residual.] 8 waves, BK=128, 2-deep unified stage,
// steady vmcnt(2), 128B rows, slot^(row&7) swizzle, XCD-pinned batches.
__global__ __launch_bounds__(512) void cheb_mm_kernel(
    const char* __restrict__ A8,
    const char* __restrict__ Uq,
    const float* __restrict__ dvec,
    const unsigned short* __restrict__ prevb,   // nullable
    unsigned short* __restrict__ Tbout,
    char* __restrict__ Uqout,                   // nullable
    float cs) {
  __shared__ char lds[32768];  // A: 2x8K @0; U: 2x8K @16384
  int bid = blockIdx.x;
  int slot = bid >> 3;
  int b = (bid & 7) * 2 + (slot >> 5);   // XCD-pinned: 2 batches per XCD
  int tm = slot & 31;
  int tid = threadIdx.x;
  int lane = tid & 63;
  int w = tid >> 6;                      // 0..7
  int wm = w >> 1, wn = w & 1;           // 4 row-groups x 2 col-groups
  int lr = lane >> 3;                    // row 0..7 within an 8-row chunk
  int gs = (lane & 7) ^ lr;              // inverse-swizzled source slot (16B)
  int r16 = lane & 15, kq = lane >> 4;
  const int NT = NN / 128;               // 16 super-steps

  const size_t abase = ((size_t)b * NN + (size_t)tm * 64) * NN;
  const size_t ubase = (size_t)b * FF * NN;

  i32x4 acc[2] = {};   // A @ U  (ni = 0,1)

  int r = w * 8 + lr;                    // this thread's staged row 0..63
  auto stage = [&](int s, int kt) {      // 2 gloads per wave (U, A)
    int k0 = kt * 128;
    gload16(Uq + ubase + (size_t)r * NN + k0 + gs * 16,
            &lds[16384 + s * 8192 + w * 1024]);
    gload16(A8 + abase + (size_t)r * NN + k0 + gs * 16,
            &lds[s * 8192 + w * 1024]);
  };

  // prologue: both buffers (prefetch distance 2)
  stage(0, 0); stage(1, 1);
  for (int t = 0; t < NT; ++t) {
    int s = t & 1;
    if (t < NT - 1) asm volatile("s_waitcnt vmcnt(2)" ::: "memory");
    else            asm volatile("s_waitcnt vmcnt(0)" ::: "memory");
    BAR();                                  // bufs ready for all waves
    int ar = wm * 16 + r16;
#pragma unroll
    for (int j = 0; j < 2; ++j) {           // 2 k-substeps of 64
      i32x4 af = *(const i32x4*)&lds[s * 8192 + ar * 128 +
                                     (((j * 4 + kq) ^ (ar & 7)) * 16)];
#pragma unroll
      for (int ni = 0; ni < 2; ++ni) {
        int fr = wn * 32 + ni * 16 + r16;
        int fo = fr * 128 + (((j * 4 + kq) ^ (fr & 7)) * 16);
        i32x4 uf = *(const i32x4*)&lds[16384 + s * 8192 + fo];
        acc[ni] = __builtin_amdgcn_mfma_i32_16x16x64_i8(af, uf, acc[ni], 0, 0, 0);
      }
    }
    BAR();                                  // all waves done reading buf s
    if (t + 2 < NT) stage(s, t + 2);
  }

  // epilogue: D mapping col=lane&15, row=(lane>>4)*4+reg (dtype-independent)
  char (*tq)[72] = (char(*)[72])lds;       // 64 cols x 64 rows @0
  int n0 = tm * 64;
#pragma unroll
  for (int rg = 0; rg < 4; ++rg) {
    int rl = wm * 16 + kq * 4 + rg;
    int row = n0 + rl;
    float dd = dvec[b * NN + row];
    float dcs = dd * cs;
#pragma unroll
    for (int ni = 0; ni < 2; ++ni) {
      int col = wn * 32 + ni * 16 + r16;
      size_t idx = ((size_t)b * NN + row) * FF + col;
      float v = dcs * (float)acc[ni][rg];
      if (prevb) v -= bf2f(prevb[idx]);
      Tbout[idx] = f2bf(v);
      if (Uqout) {
        int q = (int)rintf(dd * v * 2048.f);
        q = q > 127 ? 127 : (q < -127 ? -127 : q);
        tq[col][rl] = (char)q;
      }
    }
  }
  if (Uqout) {
    __syncthreads();
    int f = tid >> 3, nb = (tid & 7) * 8;     // 512 threads = 64 f x 8 chunks
    unsigned long long vq = *(const unsigned long long*)&tq[f][nb];
    *(unsigned long long*)&Uqout[((size_t)b * FF + f) * NN + n0 + nb] = vq;
  }
}

// out[m][c] = relu( sum_k Z[m][k]*W[k][c] + bias[c] ), Z = [Tb0|Tb1|Tb2|Tb3]
// BM=64, BN=128, BK=64; 4 waves (2x2), wave tile 32x64; 3-deep counted-vmcnt.
__global__ __launch_bounds__(256) void final_gemm_kernel(
    const unsigned short* __restrict__ Tb,   // [4][M][64] bf16
    const unsigned short* __restrict__ WT,   // [128][256] bf16
    const float* __restrict__ bias,
    float* __restrict__ out) {
  __shared__ unsigned short lds[36864];   // A: 3 x 4096 at 0; B: 3 x 8192 at 12288
  const int M = NB * NN;
  int m0 = blockIdx.x * 64;
  int tid = threadIdx.x;
  int lane = tid & 63, w = tid >> 6;
  int wm = w >> 1, wn = w & 1;
  int lr = lane >> 3, gs = (lane & 7) ^ lr;
  int r16 = lane & 15, kq = lane >> 4;

  f32x4 acc[2][4] = {};

  auto stage = [&](int s, int kt) {   // 6 gload16 per wave
    const unsigned short* asrc = Tb + (size_t)kt * M * FF;
#pragma unroll
    for (int i = 0; i < 2; ++i) {
      int chunk = w * 2 + i;                   // 8 chunks: 64 rows
      int r = chunk * 8 + lr;
      gload16(asrc + (size_t)(m0 + r) * FF + gs * 8,
              &lds[s * 4096 + chunk * 512]);
    }
#pragma unroll
    for (int i = 0; i < 4; ++i) {
      int chunk = w * 4 + i;                   // 16 chunks: 128 c-rows
      int c = chunk * 8 + lr;
      gload16(WT + c * 256 + kt * 64 + gs * 8,
              &lds[12288 + s * 8192 + chunk * 512]);
    }
  };

  stage(0, 0); stage(1, 1); stage(2, 2);
  int s = 0;
  for (int t = 0; t < 4; ++t) {
    if (t < 2)       asm volatile("s_waitcnt vmcnt(12)" ::: "memory");
    else if (t == 2) asm volatile("s_waitcnt vmcnt(6)" ::: "memory");
    else             asm volatile("s_waitcnt vmcnt(0)" ::: "memory");
    BAR();
    bf16x8 af[2][2], bfr[4][2];
#pragma unroll
    for (int ks = 0; ks < 2; ++ks) {
#pragma unroll
      for (int mi = 0; mi < 2; ++mi) {
        int row = wm * 32 + mi * 16 + r16;
        af[mi][ks] = *(const bf16x8*)&lds[s * 4096 + row * 64 +
                                          (((ks * 4 + kq) ^ (row & 7)) * 8)];
      }
#pragma unroll
      for (int ni = 0; ni < 4; ++ni) {
        int fr = wn * 64 + ni * 16 + r16;
        bfr[ni][ks] = *(const bf16x8*)&lds[12288 + s * 8192 + fr * 64 +
                                           (((ks * 4 + kq) ^ (fr & 7)) * 8)];
      }
    }
#pragma unroll
    for (int ks = 0; ks < 2; ++ks)
#pragma unroll
      for (int mi = 0; mi < 2; ++mi)
#pragma unroll
        for (int ni = 0; ni < 4; ++ni)
          acc[mi][ni] = __builtin_amdgcn_mfma_f32_16x16x32_bf16(
              af[mi][ks], bfr[ni][ks], acc[mi][ni], 0, 0, 0);
    BAR();
    if (t + 3 < 4) stage(s, t + 3);
    s = (s == 2) ? 0 : s + 1;
  }

#pragma unroll
  for (int mi = 0; mi < 2; ++mi) {
#pragma unroll
    for (int r = 0; r < 4; ++r) {
      int row = m0 + wm * 32 + mi * 16 + kq * 4 + r;
#pragma unroll
      for (int ni = 0; ni < 4; ++ni) {
        int col = wn * 64 + ni * 16 + r16;
        float v = acc[mi][ni][r] + bias[col];
        out[(size_t)row * 128 + col] = v > 0.f ? v : 0.f;
      }
    }
  }
}

extern "C" void kernel_launch(void* const* d_in, const int* in_sizes, int n_in,
                              void* d_out, int out_size, void* d_ws, size_t ws_size,
                              hipStream_t stream) {
  const float* X    = (const float*)d_in[0];   // [16,2048,64]
  const float* A    = (const float*)d_in[1];   // [16,2048,2048]
  const float* Kr   = (const float*)d_in[2];   // [256,128]
  const float* bias = (const float*)d_in[3];   // [128]
  float* out = (float*)d_out;
  char* ws = (char*)d_ws;

  const size_t SZ_A8 = (size_t)NB * NN * NN;       // 67 MB i8 A
  const size_t SZ_D  = (size_t)NB * NN * 4;
  const size_t SZ_U  = (size_t)NB * FF * NN;       // 2 MB i8 U plane
  const size_t SZ_TB = (size_t)NB * NN * FF * 2;   // 4 MB per bf16 slab
  const size_t TBE   = (size_t)NB * NN * FF;       // elements per Tb slab

  char*           A8  = ws;
  float*          dv  = (float*)(ws + SZ_A8);
  char*           Ua  = ws + SZ_A8 + SZ_D;
  char*           Ub  = Ua + SZ_U;
  unsigned short* Tb  = (unsigned short*)(Ub + SZ_U);
  unsigned short* WT  = (unsigned short*)(Ub + SZ_U + 4 * SZ_TB);

  rowsum_conv_kernel<<<NB * NN / 4, 256, 0, stream>>>(A, A8, dv);
  // T0 = X: Ua = i8(2048*d*X); Tb0 = bf16(X); blocks 512+ convert the weight
  scale_transpose_kernel<<<640, 256, 0, stream>>>(X, dv, Ua, Tb, Kr, WT);
  // T1 = d ⊙ (A @ U0);        Tb1, Ub
  cheb_mm_kernel<<<512, 512, 0, stream>>>(A8, Ua, dv, nullptr,
                                          Tb + TBE, Ub, 1.0f * INV_SCALE);
  // T2 = 2 d ⊙ (A @ U1) - T0; Tb2, Ua
  cheb_mm_kernel<<<512, 512, 0, stream>>>(A8, Ub, dv, Tb,
                                          Tb + 2 * TBE, Ua, 2.0f * INV_SCALE);
  // T3 = 2 d ⊙ (A @ U2) - T1; Tb3
  cheb_mm_kernel<<<512, 512, 0, stream>>>(A8, Ua, dv, Tb + TBE,
                                          Tb + 3 * TBE, nullptr, 2.0f * INV_SCALE);
  final_gemm_kernel<<<512, 256, 0, stream>>>(Tb, WT, bias, out);
}